// Round 1
// baseline (3038.517 us; speedup 1.0000x reference)
//
#include <hip/hip_runtime.h>

#define NNODES 500000
#define NEDGES 16000000

// ---------------- helpers ----------------

__device__ __forceinline__ unsigned fmap_ord(float x) {
    unsigned u = __float_as_uint(x);
    return (u & 0x80000000u) ? ~u : (u | 0x80000000u);
}
__device__ __forceinline__ float funmap_ord(unsigned u) {
    unsigned bits = (u & 0x80000000u) ? (u ^ 0x80000000u) : ~u;
    return __uint_as_float(bits);
}

__device__ __forceinline__ void block_reduce_atomic4(float v0, float v1, float v2, float v3,
                                                     float* dst) {
    for (int off = 32; off > 0; off >>= 1) {
        v0 += __shfl_down(v0, off, 64);
        v1 += __shfl_down(v1, off, 64);
        v2 += __shfl_down(v2, off, 64);
        v3 += __shfl_down(v3, off, 64);
    }
    __shared__ float red[4][4];
    int lane = threadIdx.x & 63, wid = threadIdx.x >> 6;
    if (lane == 0) { red[wid][0] = v0; red[wid][1] = v1; red[wid][2] = v2; red[wid][3] = v3; }
    __syncthreads();
    if (threadIdx.x < 4) {
        float t = red[0][threadIdx.x] + red[1][threadIdx.x] + red[2][threadIdx.x] + red[3][threadIdx.x];
        unsafeAtomicAdd(&dst[threadIdx.x], t);
    }
}

// ---------------- kernels ----------------

// zero accumulation buffers (must run every call: graph replays accumulate otherwise)
__global__ __launch_bounds__(256) void k_init(float* s, float* msg, unsigned* mxb, float* accum) {
    int i = blockIdx.x * blockDim.x + threadIdx.x;
    if (i < NNODES) { s[i] = 0.f; mxb[i] = 0u; }
    if (i < 2 * NNODES) msg[i] = 0.f;
    if (i < 16) accum[i] = 0.f;
}

// per-node linears: q, k, v
__global__ __launch_bounds__(256) void k_node_prep(
    const float* __restrict__ x,
    const float* __restrict__ Wq, const float* __restrict__ bq,
    const float* __restrict__ Wk, const float* __restrict__ bk,
    const float* __restrict__ Wv, const float* __restrict__ bv,
    float2* __restrict__ q, float4* __restrict__ kv) {
    int i = blockIdx.x * blockDim.x + threadIdx.x;
    if (i >= NNODES) return;
    float2 xv = ((const float2*)x)[i];
    float q0 = fmaf(Wq[0], xv.x, fmaf(Wq[1], xv.y, bq[0]));
    float q1 = fmaf(Wq[2], xv.x, fmaf(Wq[3], xv.y, bq[1]));
    float k0 = fmaf(Wk[0], xv.x, fmaf(Wk[1], xv.y, bk[0]));
    float k1 = fmaf(Wk[2], xv.x, fmaf(Wk[3], xv.y, bk[1]));
    float v0 = fmaf(Wv[0], xv.x, fmaf(Wv[1], xv.y, bv[0]));
    float v1 = fmaf(Wv[2], xv.x, fmaf(Wv[3], xv.y, bv[1]));
    q[i] = make_float2(q0, q1);
    kv[i] = make_float4(k0, k1, v0, v1);
}

// edge pass 1: attention logits + exp + accumulate s[dst], msg[dst]
__global__ __launch_bounds__(256) void k_edge_attn(
    const int* __restrict__ ei, const float* __restrict__ ea,
    const float* __restrict__ We,
    const float2* __restrict__ q, const float4* __restrict__ kv,
    float* __restrict__ s, float* __restrict__ msg) {
    float we00 = We[0], we01 = We[1], we10 = We[2], we11 = We[3];
    int stride = gridDim.x * blockDim.x;
    for (int e = blockIdx.x * blockDim.x + threadIdx.x; e < NEDGES; e += stride) {
        int si = ((const int2*)ei)[e].y;                     // edge_index[0, 2e+1]
        int di = ((const int2*)(ei + 2 * NEDGES))[e].y;     // edge_index[1, 2e+1]
        float2 eav = ((const float2*)ea)[2 * e + 1];        // edge_attr row 2e+1
        float e0 = fmaf(we00, eav.x, we01 * eav.y);
        float e1 = fmaf(we10, eav.x, we11 * eav.y);
        float4 kvv = kv[si];
        float2 qv = q[di];
        float kj0 = kvv.x + e0, kj1 = kvv.y + e1;
        float alpha = fmaf(qv.x, kj0, qv.y * kj1) * 0.70710678118654752f;
        float a = __expf(alpha);
        unsafeAtomicAdd(&s[di], a);
        unsafeAtomicAdd(&msg[2 * di], a * (kvv.z + e0));
        unsafeAtomicAdd(&msg[2 * di + 1], a * (kvv.w + e1));
    }
}

// per-node: finalize conv (msg/s + skip), store h in msg buffer, reduce mean/var sums
__global__ __launch_bounds__(256) void k_node_h(
    const float* __restrict__ x,
    const float* __restrict__ Wskip, const float* __restrict__ bskip,
    const float* __restrict__ s, float* __restrict__ msg, float* __restrict__ accum) {
    int i = blockIdx.x * blockDim.x + threadIdx.x;
    float h0 = 0.f, h1 = 0.f;
    if (i < NNODES) {
        float2 xv = ((const float2*)x)[i];
        float sk0 = fmaf(Wskip[0], xv.x, fmaf(Wskip[1], xv.y, bskip[0]));
        float sk1 = fmaf(Wskip[2], xv.x, fmaf(Wskip[3], xv.y, bskip[1]));
        float sv = s[i];
        float inv = sv > 0.f ? 1.f / sv : 0.f;
        h0 = fmaf(msg[2 * i], inv, sk0);
        h1 = fmaf(msg[2 * i + 1], inv, sk1);
        msg[2 * i] = h0;
        msg[2 * i + 1] = h1;
    }
    block_reduce_atomic4(h0, h1, h0 * h0, h1 * h1, accum);
}

// 1-thread: layernorm scale/shift
__global__ void k_ln_final(const float* __restrict__ gamma, const float* __restrict__ beta,
                           float* __restrict__ accum) {
    float n = (float)NNODES;
    float mu0 = accum[0] / n, mu1 = accum[1] / n;
    float var0 = accum[2] / n - mu0 * mu0;
    float var1 = accum[3] / n - mu1 * mu1;
    float sc0 = gamma[0] * rsqrtf(var0 + 1e-5f);
    float sc1 = gamma[1] * rsqrtf(var1 + 1e-5f);
    accum[8] = sc0;
    accum[9] = sc1;
    accum[10] = beta[0] - mu0 * sc0;
    accum[11] = beta[1] - mu1 * sc1;
}

// per-node: normalized h -> exp, store p (unnormalized softmax), reduce column sums
__global__ __launch_bounds__(256) void k_softmax_exp(
    const float* __restrict__ h, float2* __restrict__ p, float* __restrict__ accum) {
    int i = blockIdx.x * blockDim.x + threadIdx.x;
    float p0 = 0.f, p1 = 0.f;
    if (i < NNODES) {
        float sc0 = accum[8], sc1 = accum[9], sh0 = accum[10], sh1 = accum[11];
        p0 = __expf(fmaf(h[2 * i], sc0, sh0));
        p1 = __expf(fmaf(h[2 * i + 1], sc1, sh1));
        p[i] = make_float2(p0, p1);
    }
    block_reduce_atomic4(p0, p1, 0.f, 0.f, accum + 4);
}

// 1-thread: softmax denominators -> reciprocals
__global__ void k_sm_final(float* __restrict__ accum) {
    accum[12] = 1.f / accum[4];
    accum[13] = 1.f / accum[5];
}

// edge pass 2: neighbor max of h_soft[src] . ea_clause
__global__ __launch_bounds__(256) void k_edge_nmax(
    const int* __restrict__ ei, const float* __restrict__ ea,
    const float2* __restrict__ p, const float* __restrict__ accum,
    unsigned* __restrict__ mxb) {
    float inv0 = accum[12], inv1 = accum[13];
    int stride = gridDim.x * blockDim.x;
    for (int e = blockIdx.x * blockDim.x + threadIdx.x; e < NEDGES; e += stride) {
        int si = ((const int2*)ei)[e].y;
        int di = ((const int2*)(ei + 2 * NEDGES))[e].y;
        float2 c = ((const float2*)ea)[2 * e];              // edge_attr row 2e (clause)
        float2 pv = p[si];
        float sE = fmaf(pv.x * inv0, c.x, pv.y * inv1 * c.y);
        atomicMax(&mxb[di], fmap_ord(sE));
    }
}

// final per-node output
__global__ __launch_bounds__(256) void k_final(
    const unsigned* __restrict__ mxb, const float2* __restrict__ p,
    const float* __restrict__ accum,
    const float* __restrict__ Wf, const float* __restrict__ bf,
    const float* __restrict__ mask, float* __restrict__ out) {
    int i = blockIdx.x * blockDim.x + threadIdx.x;
    if (i >= NNODES) return;
    float wf0 = Wf[0], wf1 = Wf[1], b = bf[0];
    unsigned m = mxb[i];
    float h0, h1;
    if (m != 0u) {
        float v = funmap_ord(m);
        h0 = v;
        h1 = 1.f - v;
    } else {
        float2 pv = p[i];
        h0 = pv.x * accum[12];
        h1 = pv.y * accum[13];
    }
    out[i] = fmaf(wf0, h0, fmaf(wf1, h1, b)) * mask[i];
}

// ---------------- launch ----------------

extern "C" void kernel_launch(void* const* d_in, const int* in_sizes, int n_in,
                              void* d_out, int out_size, void* d_ws, size_t ws_size,
                              hipStream_t stream) {
    const float* x     = (const float*)d_in[0];
    const int*   ei    = (const int*)d_in[1];
    const float* ea    = (const float*)d_in[2];
    const float* mask  = (const float*)d_in[3];
    const float* Wq    = (const float*)d_in[4];
    const float* bq    = (const float*)d_in[5];
    const float* Wk    = (const float*)d_in[6];
    const float* bk    = (const float*)d_in[7];
    const float* Wv    = (const float*)d_in[8];
    const float* bv    = (const float*)d_in[9];
    const float* We    = (const float*)d_in[10];
    const float* Wskip = (const float*)d_in[11];
    const float* bskip = (const float*)d_in[12];
    const float* gamma = (const float*)d_in[13];
    const float* beta  = (const float*)d_in[14];
    const float* Wf    = (const float*)d_in[15];
    const float* bf    = (const float*)d_in[16];
    float* out = (float*)d_out;

    // ws layout (floats): q/p 2N | kv 4N | s N | msg/h 2N | mxb N (uint) | accum 16
    float* q   = (float*)d_ws;
    float* kv  = q + 2 * NNODES;
    float* s   = kv + 4 * NNODES;
    float* msg = s + NNODES;
    unsigned* mxb = (unsigned*)(msg + 2 * NNODES);
    float* accum  = (float*)(mxb + NNODES);

    const int B = 256;
    int gridN  = (NNODES + B - 1) / B;
    int grid2N = (2 * NNODES + B - 1) / B;
    int gridE  = 4096;

    k_init<<<grid2N, B, 0, stream>>>(s, msg, mxb, accum);
    k_node_prep<<<gridN, B, 0, stream>>>(x, Wq, bq, Wk, bk, Wv, bv, (float2*)q, (float4*)kv);
    k_edge_attn<<<gridE, B, 0, stream>>>(ei, ea, We, (const float2*)q, (const float4*)kv, s, msg);
    k_node_h<<<gridN, B, 0, stream>>>(x, Wskip, bskip, s, msg, accum);
    k_ln_final<<<1, 1, 0, stream>>>(gamma, beta, accum);
    k_softmax_exp<<<gridN, B, 0, stream>>>(msg, (float2*)q, accum);
    k_sm_final<<<1, 1, 0, stream>>>(accum);
    k_edge_nmax<<<gridE, B, 0, stream>>>(ei, ea, (const float2*)q, accum, mxb);
    k_final<<<gridN, B, 0, stream>>>(mxb, (const float2*)q, accum, Wf, bf, mask, out);
}

// Round 2
// 3033.981 us; speedup vs baseline: 1.0015x; 1.0015x over previous
//
#include <hip/hip_runtime.h>

#define NNODES 500000
#define NEDGES 16000000

// ---------------- helpers ----------------

__device__ __forceinline__ unsigned fmap_ord(float x) {
    unsigned u = __float_as_uint(x);
    return (u & 0x80000000u) ? ~u : (u | 0x80000000u);
}
__device__ __forceinline__ float funmap_ord(unsigned u) {
    unsigned bits = (u & 0x80000000u) ? (u ^ 0x80000000u) : ~u;
    return __uint_as_float(bits);
}

__device__ __forceinline__ void block_reduce_atomic4(float v0, float v1, float v2, float v3,
                                                     float* dst) {
    for (int off = 32; off > 0; off >>= 1) {
        v0 += __shfl_down(v0, off, 64);
        v1 += __shfl_down(v1, off, 64);
        v2 += __shfl_down(v2, off, 64);
        v3 += __shfl_down(v3, off, 64);
    }
    __shared__ float red[4][4];
    int lane = threadIdx.x & 63, wid = threadIdx.x >> 6;
    if (lane == 0) { red[wid][0] = v0; red[wid][1] = v1; red[wid][2] = v2; red[wid][3] = v3; }
    __syncthreads();
    if (threadIdx.x < 4) {
        float t = red[0][threadIdx.x] + red[1][threadIdx.x] + red[2][threadIdx.x] + red[3][threadIdx.x];
        unsafeAtomicAdd(&dst[threadIdx.x], t);
    }
}

// ---------------- kernels ----------------

// zero accumulation buffers (must run every call: graph replays accumulate otherwise)
__global__ __launch_bounds__(256) void k_init(float* s, float* msg, unsigned* mxb, float* accum) {
    int i = blockIdx.x * blockDim.x + threadIdx.x;
    if (i < NNODES) { s[i] = 0.f; mxb[i] = 0u; }
    if (i < 2 * NNODES) msg[i] = 0.f;
    if (i < 16) accum[i] = 0.f;
}

// per-node linears: q, k, v
__global__ __launch_bounds__(256) void k_node_prep(
    const float* __restrict__ x,
    const float* __restrict__ Wq, const float* __restrict__ bq,
    const float* __restrict__ Wk, const float* __restrict__ bk,
    const float* __restrict__ Wv, const float* __restrict__ bv,
    float2* __restrict__ q, float4* __restrict__ kv) {
    int i = blockIdx.x * blockDim.x + threadIdx.x;
    if (i >= NNODES) return;
    float2 xv = ((const float2*)x)[i];
    float q0 = fmaf(Wq[0], xv.x, fmaf(Wq[1], xv.y, bq[0]));
    float q1 = fmaf(Wq[2], xv.x, fmaf(Wq[3], xv.y, bq[1]));
    float k0 = fmaf(Wk[0], xv.x, fmaf(Wk[1], xv.y, bk[0]));
    float k1 = fmaf(Wk[2], xv.x, fmaf(Wk[3], xv.y, bk[1]));
    float v0 = fmaf(Wv[0], xv.x, fmaf(Wv[1], xv.y, bv[0]));
    float v1 = fmaf(Wv[2], xv.x, fmaf(Wv[3], xv.y, bv[1]));
    q[i] = make_float2(q0, q1);
    kv[i] = make_float4(k0, k1, v0, v1);
}

// edge pass 1: one edge per thread — latency fully hidden by TLP, no vmcnt FIFO
// coupling between iterations (wave exits after its 3 fire-and-forget atomics).
__global__ __launch_bounds__(256) void k_edge_attn(
    const int* __restrict__ ei, const float* __restrict__ ea,
    const float* __restrict__ We,
    const float2* __restrict__ q, const float4* __restrict__ kv,
    float* __restrict__ s, float* __restrict__ msg) {
    int e = blockIdx.x * blockDim.x + threadIdx.x;
    if (e >= NEDGES) return;
    float we00 = We[0], we01 = We[1], we10 = We[2], we11 = We[3];
    int si = ((const int2*)ei)[e].y;                    // edge_index[0, 2e+1]
    int di = ((const int2*)(ei + 2 * NEDGES))[e].y;     // edge_index[1, 2e+1]
    float2 eav = ((const float2*)ea)[2 * e + 1];        // edge_attr row 2e+1
    float4 kvv = kv[si];
    float2 qv = q[di];
    float e0 = fmaf(we00, eav.x, we01 * eav.y);
    float e1 = fmaf(we10, eav.x, we11 * eav.y);
    float kj0 = kvv.x + e0, kj1 = kvv.y + e1;
    float alpha = fmaf(qv.x, kj0, qv.y * kj1) * 0.70710678118654752f;
    float a = __expf(alpha);
    unsafeAtomicAdd(&s[di], a);
    unsafeAtomicAdd(&msg[2 * di], a * (kvv.z + e0));
    unsafeAtomicAdd(&msg[2 * di + 1], a * (kvv.w + e1));
}

// per-node: finalize conv (msg/s + skip), store h in msg buffer, reduce mean/var sums
__global__ __launch_bounds__(256) void k_node_h(
    const float* __restrict__ x,
    const float* __restrict__ Wskip, const float* __restrict__ bskip,
    const float* __restrict__ s, float* __restrict__ msg, float* __restrict__ accum) {
    int i = blockIdx.x * blockDim.x + threadIdx.x;
    float h0 = 0.f, h1 = 0.f;
    if (i < NNODES) {
        float2 xv = ((const float2*)x)[i];
        float sk0 = fmaf(Wskip[0], xv.x, fmaf(Wskip[1], xv.y, bskip[0]));
        float sk1 = fmaf(Wskip[2], xv.x, fmaf(Wskip[3], xv.y, bskip[1]));
        float sv = s[i];
        float inv = sv > 0.f ? 1.f / sv : 0.f;
        h0 = fmaf(msg[2 * i], inv, sk0);
        h1 = fmaf(msg[2 * i + 1], inv, sk1);
        msg[2 * i] = h0;
        msg[2 * i + 1] = h1;
    }
    block_reduce_atomic4(h0, h1, h0 * h0, h1 * h1, accum);
}

// 1-thread: layernorm scale/shift
__global__ void k_ln_final(const float* __restrict__ gamma, const float* __restrict__ beta,
                           float* __restrict__ accum) {
    float n = (float)NNODES;
    float mu0 = accum[0] / n, mu1 = accum[1] / n;
    float var0 = accum[2] / n - mu0 * mu0;
    float var1 = accum[3] / n - mu1 * mu1;
    float sc0 = gamma[0] * rsqrtf(var0 + 1e-5f);
    float sc1 = gamma[1] * rsqrtf(var1 + 1e-5f);
    accum[8] = sc0;
    accum[9] = sc1;
    accum[10] = beta[0] - mu0 * sc0;
    accum[11] = beta[1] - mu1 * sc1;
}

// per-node: normalized h -> exp, store p (unnormalized softmax), reduce column sums
__global__ __launch_bounds__(256) void k_softmax_exp(
    const float* __restrict__ h, float2* __restrict__ p, float* __restrict__ accum) {
    int i = blockIdx.x * blockDim.x + threadIdx.x;
    float p0 = 0.f, p1 = 0.f;
    if (i < NNODES) {
        float sc0 = accum[8], sc1 = accum[9], sh0 = accum[10], sh1 = accum[11];
        p0 = __expf(fmaf(h[2 * i], sc0, sh0));
        p1 = __expf(fmaf(h[2 * i + 1], sc1, sh1));
        p[i] = make_float2(p0, p1);
    }
    block_reduce_atomic4(p0, p1, 0.f, 0.f, accum + 4);
}

// 1-thread: softmax denominators -> reciprocals
__global__ void k_sm_final(float* __restrict__ accum) {
    accum[12] = 1.f / accum[4];
    accum[13] = 1.f / accum[5];
}

// edge pass 2: one edge per thread — neighbor max of h_soft[src] . ea_clause
__global__ __launch_bounds__(256) void k_edge_nmax(
    const int* __restrict__ ei, const float* __restrict__ ea,
    const float2* __restrict__ p, const float* __restrict__ accum,
    unsigned* __restrict__ mxb) {
    int e = blockIdx.x * blockDim.x + threadIdx.x;
    if (e >= NEDGES) return;
    float inv0 = accum[12], inv1 = accum[13];
    int si = ((const int2*)ei)[e].y;
    int di = ((const int2*)(ei + 2 * NEDGES))[e].y;
    float2 c = ((const float2*)ea)[2 * e];              // edge_attr row 2e (clause)
    float2 pv = p[si];
    float sE = fmaf(pv.x * inv0, c.x, pv.y * inv1 * c.y);
    atomicMax(&mxb[di], fmap_ord(sE));
}

// final per-node output
__global__ __launch_bounds__(256) void k_final(
    const unsigned* __restrict__ mxb, const float2* __restrict__ p,
    const float* __restrict__ accum,
    const float* __restrict__ Wf, const float* __restrict__ bf,
    const float* __restrict__ mask, float* __restrict__ out) {
    int i = blockIdx.x * blockDim.x + threadIdx.x;
    if (i >= NNODES) return;
    float wf0 = Wf[0], wf1 = Wf[1], b = bf[0];
    unsigned m = mxb[i];
    float h0, h1;
    if (m != 0u) {
        float v = funmap_ord(m);
        h0 = v;
        h1 = 1.f - v;
    } else {
        float2 pv = p[i];
        h0 = pv.x * accum[12];
        h1 = pv.y * accum[13];
    }
    out[i] = fmaf(wf0, h0, fmaf(wf1, h1, b)) * mask[i];
}

// ---------------- launch ----------------

extern "C" void kernel_launch(void* const* d_in, const int* in_sizes, int n_in,
                              void* d_out, int out_size, void* d_ws, size_t ws_size,
                              hipStream_t stream) {
    const float* x     = (const float*)d_in[0];
    const int*   ei    = (const int*)d_in[1];
    const float* ea    = (const float*)d_in[2];
    const float* mask  = (const float*)d_in[3];
    const float* Wq    = (const float*)d_in[4];
    const float* bq    = (const float*)d_in[5];
    const float* Wk    = (const float*)d_in[6];
    const float* bk    = (const float*)d_in[7];
    const float* Wv    = (const float*)d_in[8];
    const float* bv    = (const float*)d_in[9];
    const float* We    = (const float*)d_in[10];
    const float* Wskip = (const float*)d_in[11];
    const float* bskip = (const float*)d_in[12];
    const float* gamma = (const float*)d_in[13];
    const float* beta  = (const float*)d_in[14];
    const float* Wf    = (const float*)d_in[15];
    const float* bf    = (const float*)d_in[16];
    float* out = (float*)d_out;

    // ws layout (floats): q/p 2N | kv 4N | s N | msg/h 2N | mxb N (uint) | accum 16
    float* q   = (float*)d_ws;
    float* kv  = q + 2 * NNODES;
    float* s   = kv + 4 * NNODES;
    float* msg = s + NNODES;
    unsigned* mxb = (unsigned*)(msg + 2 * NNODES);
    float* accum  = (float*)(mxb + NNODES);

    const int B = 256;
    int gridN  = (NNODES + B - 1) / B;
    int grid2N = (2 * NNODES + B - 1) / B;
    int gridE  = (NEDGES + B - 1) / B;

    k_init<<<grid2N, B, 0, stream>>>(s, msg, mxb, accum);
    k_node_prep<<<gridN, B, 0, stream>>>(x, Wq, bq, Wk, bk, Wv, bv, (float2*)q, (float4*)kv);
    k_edge_attn<<<gridE, B, 0, stream>>>(ei, ea, We, (const float2*)q, (const float4*)kv, s, msg);
    k_node_h<<<gridN, B, 0, stream>>>(x, Wskip, bskip, s, msg, accum);
    k_ln_final<<<1, 1, 0, stream>>>(gamma, beta, accum);
    k_softmax_exp<<<gridN, B, 0, stream>>>(msg, (float2*)q, accum);
    k_sm_final<<<1, 1, 0, stream>>>(accum);
    k_edge_nmax<<<gridE, B, 0, stream>>>(ei, ea, (const float2*)q, accum, mxb);
    k_final<<<gridN, B, 0, stream>>>(mxb, (const float2*)q, accum, Wf, bf, mask, out);
}